// Round 1
// 735.269 us; speedup vs baseline: 1.0015x; 1.0015x over previous
//
#include <hip/hip_runtime.h>
#include <hip/hip_bf16.h>
#include <math.h>

#define B_    4
#define N_    200000
#define E_    128
#define IDX_  2048
#define TT    (B_*N_)
#define INV_NORM 0.08838834764831845f   /* 1/sqrt(128) */
#define CAP   512
#define RCAP  8                         /* 8*64 = 512 tokens in-register */
#define WPAD  136                       /* bf16 elems per W row in LDS */

typedef __attribute__((ext_vector_type(8))) short bf16x8;
typedef __attribute__((ext_vector_type(4))) float f32x4;

__device__ __forceinline__ unsigned short f2bf(float f) {
    unsigned int u = __float_as_uint(f);
    unsigned int r = (u + 0x7fffu + ((u >> 16) & 1u)) >> 16;
    return (unsigned short)r;
}

/* ---- Kernel A: scores via bf16 MFMA + fused histogram ----
 * s = mask ? ctx.tanh(x@W^T+b)/sqrt(E) : -1e9 ;  counts[b,idx]++
 * epilogue identity: ctx.tanh(v) = sum(ctx) - 2*sum(ctx/(1+e^{2v})) */
__global__ __launch_bounds__(256) void score_kernel(
    const float* __restrict__ x, const float* __restrict__ W,
    const float* __restrict__ bias, const float* __restrict__ ctx,
    const int* __restrict__ mask, const int* __restrict__ index,
    float* __restrict__ scores, int* __restrict__ counts)
{
    __shared__ unsigned short Wb[E_ * WPAD];   /* 34816 B */

    const int tid = threadIdx.x;

    /* stage W: fp32 global -> bf16 LDS (once per block) */
    for (int i = tid; i < E_ * E_ / 4; i += 256) {
        int f = i >> 5, kb = (i & 31) * 4;
        float4 v = ((const float4*)W)[i];
        ushort4 o;
        o.x = f2bf(v.x); o.y = f2bf(v.y); o.z = f2bf(v.z); o.w = f2bf(v.w);
        *(ushort4*)&Wb[f * WPAD + kb] = o;
    }
    __syncthreads();

    const int lane = tid & 63;
    const int col  = lane & 15;      /* feature-within-ntile / token-within-mtile */
    const int q    = lane >> 4;      /* quad: k-subrange for A/B, row-group for C */
    const int wave = tid >> 6;

    /* per-lane ctx / 2*bias for features n*16+col; csum = sum of this lane's ctx */
    float ctx_r[8], bias2[8], csum = 0.f;
#pragma unroll
    for (int n = 0; n < 8; n++) {
        ctx_r[n] = ctx[n * 16 + col];
        bias2[n] = 2.f * bias[n * 16 + col];
        csum += ctx_r[n];
    }
    const float csum_n = csum * INV_NORM;

    /* persistent B fragments: Bf[n][kt] = W[n*16+col][kt*32+q*8 .. +7] */
    bf16x8 Bf[8][4];
#pragma unroll
    for (int n = 0; n < 8; n++)
#pragma unroll
        for (int kt = 0; kt < 4; kt++)
            Bf[n][kt] = *(const bf16x8*)&Wb[(n * 16 + col) * WPAD + kt * 32 + q * 8];

    for (long base0 = (long)blockIdx.x * 64; base0 < TT; base0 += (long)gridDim.x * 64) {
        const long tbase = base0 + wave * 16;
        const float* xrow = x + (tbase + col) * (long)E_;

        /* A fragments: Af[kt] = x[tbase+col][kt*32+q*8 .. +7], fp32->bf16 packed */
        bf16x8 Af[4];
#pragma unroll
        for (int kt = 0; kt < 4; kt++) {
            float4 u = ((const float4*)xrow)[kt * 8 + q * 2];
            float4 v = ((const float4*)xrow)[kt * 8 + q * 2 + 1];
            union { bf16x8 vec; __hip_bfloat162 h[4]; } a;
            a.h[0] = __float22bfloat162_rn(make_float2(u.x, u.y));
            a.h[1] = __float22bfloat162_rn(make_float2(u.z, u.w));
            a.h[2] = __float22bfloat162_rn(make_float2(v.x, v.y));
            a.h[3] = __float22bfloat162_rn(make_float2(v.z, v.w));
            Af[kt] = a.vec;
        }

        f32x4 acc[8];
#pragma unroll
        for (int n = 0; n < 8; n++) acc[n] = (f32x4){0.f, 0.f, 0.f, 0.f};

#pragma unroll
        for (int kt = 0; kt < 4; kt++)
#pragma unroll
            for (int n = 0; n < 8; n++)
                acc[n] = __builtin_amdgcn_mfma_f32_16x16x32_bf16(Af[kt], Bf[n][kt], acc[n], 0, 0, 0);

        /* epilogue: p_r = csum_n - 2*INV_NORM * sum_n ctx_n/(1+e^{2(acc+bias)}) */
        float pr[4];
#pragma unroll
        for (int r = 0; r < 4; r++) {
            float psum = 0.f;
#pragma unroll
            for (int n = 0; n < 8; n++) {
                float t = fmaf(acc[n][r], 2.f, bias2[n]);
                float rc = __builtin_amdgcn_rcpf(1.f + __expf(t));
                psum = fmaf(ctx_r[n], rc, psum);
            }
            float p = fmaf(-2.f * INV_NORM, psum, csum_n);
#pragma unroll
            for (int o = 1; o < 16; o <<= 1) p += __shfl_xor(p, o);
            pr[r] = p;
        }
        if (col == 0) {
            int4 mv = ((const int4*)(mask + tbase))[q];
            float4 s;
            s.x = mv.x ? pr[0] : -1e9f;
            s.y = mv.y ? pr[1] : -1e9f;
            s.z = mv.z ? pr[2] : -1e9f;
            s.w = mv.w ? pr[3] : -1e9f;
            ((float4*)(scores + tbase))[q] = s;

            /* fused histogram (all tokens, mask-independent) */
            int4 iv = ((const int4*)(index + tbase))[q];
            int* cb = counts + (int)(tbase / N_) * IDX_;
            atomicAdd(&cb[iv.x], 1);
            atomicAdd(&cb[iv.y], 1);
            atomicAdd(&cb[iv.z], 1);
            atomicAdd(&cb[iv.w], 1);
        }
    }
}

/* ---------------- Kernel C: exclusive scan over 8192 counters --------------- */
__global__ __launch_bounds__(1024) void scan_kernel(
    const int* __restrict__ counts, int* __restrict__ offsets, int* __restrict__ cursor)
{
    __shared__ int sums[1024];
    int tid = threadIdx.x;
    int c[8], loc[8], s = 0;
#pragma unroll
    for (int j = 0; j < 8; j++) { c[j] = counts[tid * 8 + j]; loc[j] = s; s += c[j]; }
    sums[tid] = s;
    __syncthreads();
    for (int off = 1; off < 1024; off <<= 1) {
        int v = (tid >= off) ? sums[tid - off] : 0;
        __syncthreads();
        if (tid >= off) sums[tid] += v;
        __syncthreads();
    }
    int base = (tid > 0) ? sums[tid - 1] : 0;
#pragma unroll
    for (int j = 0; j < 8; j++) {
        int o = base + loc[j];
        offsets[tid * 8 + j] = o;
        cursor[tid * 8 + j]  = o;
    }
}

/* -------- Kernel D: scatter (token, score) pairs into segment lists --------
 * Reads index & scores COALESCED (linear token walk); the scattered part is
 * one int2 write per token. This removes the random 4B score gather that sat
 * on attend's critical path. */
__global__ __launch_bounds__(256) void scatter_kernel(
    const int* __restrict__ index, const float* __restrict__ scores,
    int* __restrict__ cursor, int2* __restrict__ tokenlist)
{
    for (int tok = blockIdx.x * blockDim.x + threadIdx.x; tok < TT;
         tok += gridDim.x * blockDim.x) {
        int seg = index[tok];
        float s = scores[tok];
        int b   = tok / N_;
        int pos = atomicAdd(&cursor[b * IDX_ + seg], 1);
        tokenlist[pos] = make_int2(tok, __float_as_int(s));
    }
}

/* -------- Kernel E: wave-per-segment softmax + weighted sum ----------------
 * 256 threads = 4 independent waves, each owning one (b,seg). No
 * __syncthreads anywhere: shuffle-only reductions, scores live in registers
 * (up to 512 tokens), per-wave LDS (t,w) pair buffer consumed at uniform
 * address (hardware broadcast, conflict-free). x gather = 4-deep unrolled
 * float2 loads (512 B per wave-load), 32 independent streams per CU. */
__global__ __launch_bounds__(256) void attend_kernel(
    const float* __restrict__ x, const int* __restrict__ counts,
    const int* __restrict__ offsets, const int2* __restrict__ tokenlist,
    float* __restrict__ attn /* out: weights */, float* __restrict__ out)
{
    const int wave = threadIdx.x >> 6;
    const int lane = threadIdx.x & 63;
    const int key  = blockIdx.x * 4 + wave;   /* b*IDX + seg */
    const int cnt  = counts[key];
    const int off  = offsets[key];
    const float2* __restrict__ x2 = (const float2*)x;
    float2* out2 = (float2*)(out + (size_t)key * E_);

    __shared__ int2 pair[4][CAP];   /* 16 KiB, one slice per wave */

    if (cnt == 0) { out2[lane] = make_float2(0.f, 0.f); return; }

    if (cnt <= CAP) {
        /* ---- fast path: (t,s) in registers ---- */
        int   tk[RCAP];
        float sc[RCAP], ev[RCAP];
        float m = -INFINITY;
#pragma unroll
        for (int u = 0; u < RCAP; u++) {
            int j = lane + u * 64;
            if (j < cnt) {
                int2 p = tokenlist[off + j];
                tk[u] = p.x;
                sc[u] = __int_as_float(p.y);
                m = fmaxf(m, sc[u]);
            }
        }
#pragma unroll
        for (int o = 32; o; o >>= 1) m = fmaxf(m, __shfl_xor(m, o));

        float sum = 0.f;
#pragma unroll
        for (int u = 0; u < RCAP; u++) {
            int j = lane + u * 64;
            if (j < cnt) { ev[u] = __expf(sc[u] - m); sum += ev[u]; }
        }
#pragma unroll
        for (int o = 32; o; o >>= 1) sum += __shfl_xor(sum, o);
        const float inv = 1.f / sum;

#pragma unroll
        for (int u = 0; u < RCAP; u++) {
            int j = lane + u * 64;
            if (j < cnt) {
                float w = ev[u] * inv;
                attn[tk[u]] = w;                       /* weights output */
                pair[wave][j] = make_int2(tk[u], __float_as_int(w));
            }
        }
        /* wave-synchronous: compiler inserts lgkmcnt before the reads below */

        float2 acc = make_float2(0.f, 0.f);
        int j = 0;
        for (; j + 3 < cnt; j += 4) {
            int2 p0 = pair[wave][j];
            int2 p1 = pair[wave][j + 1];
            int2 p2 = pair[wave][j + 2];
            int2 p3 = pair[wave][j + 3];
            float2 a0 = x2[(size_t)p0.x * 64 + lane];
            float2 a1 = x2[(size_t)p1.x * 64 + lane];
            float2 a2 = x2[(size_t)p2.x * 64 + lane];
            float2 a3 = x2[(size_t)p3.x * 64 + lane];
            float w0 = __int_as_float(p0.y), w1 = __int_as_float(p1.y);
            float w2 = __int_as_float(p2.y), w3 = __int_as_float(p3.y);
            acc.x = fmaf(w0, a0.x, acc.x); acc.y = fmaf(w0, a0.y, acc.y);
            acc.x = fmaf(w1, a1.x, acc.x); acc.y = fmaf(w1, a1.y, acc.y);
            acc.x = fmaf(w2, a2.x, acc.x); acc.y = fmaf(w2, a2.y, acc.y);
            acc.x = fmaf(w3, a3.x, acc.x); acc.y = fmaf(w3, a3.y, acc.y);
        }
        for (; j < cnt; j++) {
            int2  p = pair[wave][j];
            float2 a = x2[(size_t)p.x * 64 + lane];
            float w = __int_as_float(p.y);
            acc.x = fmaf(w, a.x, acc.x); acc.y = fmaf(w, a.y, acc.y);
        }
        out2[lane] = acc;
    } else {
        /* ---- slow path (cnt > CAP): never taken at these sizes ---- */
        float m = -INFINITY;
        for (int j = lane; j < cnt; j += 64)
            m = fmaxf(m, __int_as_float(tokenlist[off + j].y));
#pragma unroll
        for (int o = 32; o; o >>= 1) m = fmaxf(m, __shfl_xor(m, o));

        float sum = 0.f;
        for (int j = lane; j < cnt; j += 64)
            sum += __expf(__int_as_float(tokenlist[off + j].y) - m);
#pragma unroll
        for (int o = 32; o; o >>= 1) sum += __shfl_xor(sum, o);
        const float inv = 1.f / sum;

        float2 acc = make_float2(0.f, 0.f);
        for (int j0 = 0; j0 < cnt; j0 += 64) {
            int t = 0; float w = 0.f;
            if (j0 + lane < cnt) {
                int2 p = tokenlist[off + j0 + lane];
                t = p.x;
                w = __expf(__int_as_float(p.y) - m) * inv;
                attn[t] = w;
            }
            int lim = min(64, cnt - j0);
            for (int jj = 0; jj < lim; jj++) {
                int   tb = __shfl(t, jj);
                float wb = __shfl(w, jj);
                float2 a = x2[(size_t)tb * 64 + lane];
                acc.x = fmaf(wb, a.x, acc.x);
                acc.y = fmaf(wb, a.y, acc.y);
            }
        }
        out2[lane] = acc;
    }
}

extern "C" void kernel_launch(void* const* d_in, const int* in_sizes, int n_in,
                              void* d_out, int out_size, void* d_ws, size_t ws_size,
                              hipStream_t stream)
{
    const float* x    = (const float*)d_in[0];
    const float* W    = (const float*)d_in[1];
    const float* bias = (const float*)d_in[2];
    const float* ctx  = (const float*)d_in[3];
    const int*   mask = (const int*)d_in[4];
    const int*   index= (const int*)d_in[5];

    float* out  = (float*)d_out;                         /* B*IDX*E */
    float* attn = out + (size_t)B_ * IDX_ * E_;          /* B*N: scores then weights */

    int* counts    = (int*)d_ws;
    int* offsets   = counts  + B_ * IDX_;
    int* cursor    = offsets + B_ * IDX_;
    int2* tokenlist = (int2*)(cursor + B_ * IDX_);       /* TT * 8 B */

    hipMemsetAsync(counts, 0, B_ * IDX_ * sizeof(int), stream);
    score_kernel  <<<2048, 256, 0, stream>>>(x, W, bias, ctx, mask, index, attn, counts);
    scan_kernel   <<<1, 1024, 0, stream>>>(counts, offsets, cursor);
    scatter_kernel<<<1024, 256, 0, stream>>>(index, attn, cursor, tokenlist);
    attend_kernel <<<B_ * IDX_ / 4, 256, 0, stream>>>(x, counts, offsets, tokenlist, attn, out);
}

// Round 2
// 698.612 us; speedup vs baseline: 1.0540x; 1.0525x over previous
//
#include <hip/hip_runtime.h>
#include <hip/hip_bf16.h>
#include <math.h>

#define B_    4
#define N_    200000
#define E_    128
#define IDX_  2048
#define TT    (B_*N_)
#define INV_NORM 0.08838834764831845f   /* 1/sqrt(128) */
#define CAP   512
#define RCAP  8                         /* 8*64 = 512 tokens in-register */
#define WPAD  136                       /* bf16 elems per W row in LDS */

typedef __attribute__((ext_vector_type(8))) short bf16x8;
typedef __attribute__((ext_vector_type(4))) float f32x4;

__device__ __forceinline__ unsigned short f2bf(float f) {
    unsigned int u = __float_as_uint(f);
    unsigned int r = (u + 0x7fffu + ((u >> 16) & 1u)) >> 16;
    return (unsigned short)r;
}

/* ---- Kernel A: scores via bf16 MFMA + fused histogram ----
 * s = mask ? ctx.tanh(x@W^T+b)/sqrt(E) : -1e9 ;  counts[b,idx]++
 * epilogue identity: ctx.tanh(v) = sum(ctx) - 2*sum(ctx/(1+e^{2v})) */
__global__ __launch_bounds__(256) void score_kernel(
    const float* __restrict__ x, const float* __restrict__ W,
    const float* __restrict__ bias, const float* __restrict__ ctx,
    const int* __restrict__ mask, const int* __restrict__ index,
    float* __restrict__ scores, int* __restrict__ counts)
{
    __shared__ unsigned short Wb[E_ * WPAD];   /* 34816 B */

    const int tid = threadIdx.x;

    /* stage W: fp32 global -> bf16 LDS (once per block) */
    for (int i = tid; i < E_ * E_ / 4; i += 256) {
        int f = i >> 5, kb = (i & 31) * 4;
        float4 v = ((const float4*)W)[i];
        ushort4 o;
        o.x = f2bf(v.x); o.y = f2bf(v.y); o.z = f2bf(v.z); o.w = f2bf(v.w);
        *(ushort4*)&Wb[f * WPAD + kb] = o;
    }
    __syncthreads();

    const int lane = tid & 63;
    const int col  = lane & 15;      /* feature-within-ntile / token-within-mtile */
    const int q    = lane >> 4;      /* quad: k-subrange for A/B, row-group for C */
    const int wave = tid >> 6;

    /* per-lane ctx / 2*bias for features n*16+col; csum = sum of this lane's ctx */
    float ctx_r[8], bias2[8], csum = 0.f;
#pragma unroll
    for (int n = 0; n < 8; n++) {
        ctx_r[n] = ctx[n * 16 + col];
        bias2[n] = 2.f * bias[n * 16 + col];
        csum += ctx_r[n];
    }
    const float csum_n = csum * INV_NORM;

    /* persistent B fragments: Bf[n][kt] = W[n*16+col][kt*32+q*8 .. +7] */
    bf16x8 Bf[8][4];
#pragma unroll
    for (int n = 0; n < 8; n++)
#pragma unroll
        for (int kt = 0; kt < 4; kt++)
            Bf[n][kt] = *(const bf16x8*)&Wb[(n * 16 + col) * WPAD + kt * 32 + q * 8];

    for (long base0 = (long)blockIdx.x * 64; base0 < TT; base0 += (long)gridDim.x * 64) {
        const long tbase = base0 + wave * 16;
        const float* xrow = x + (tbase + col) * (long)E_;

        /* A fragments: Af[kt] = x[tbase+col][kt*32+q*8 .. +7], fp32->bf16 packed */
        bf16x8 Af[4];
#pragma unroll
        for (int kt = 0; kt < 4; kt++) {
            float4 u = ((const float4*)xrow)[kt * 8 + q * 2];
            float4 v = ((const float4*)xrow)[kt * 8 + q * 2 + 1];
            union { bf16x8 vec; __hip_bfloat162 h[4]; } a;
            a.h[0] = __float22bfloat162_rn(make_float2(u.x, u.y));
            a.h[1] = __float22bfloat162_rn(make_float2(u.z, u.w));
            a.h[2] = __float22bfloat162_rn(make_float2(v.x, v.y));
            a.h[3] = __float22bfloat162_rn(make_float2(v.z, v.w));
            Af[kt] = a.vec;
        }

        f32x4 acc[8];
#pragma unroll
        for (int n = 0; n < 8; n++) acc[n] = (f32x4){0.f, 0.f, 0.f, 0.f};

#pragma unroll
        for (int kt = 0; kt < 4; kt++)
#pragma unroll
            for (int n = 0; n < 8; n++)
                acc[n] = __builtin_amdgcn_mfma_f32_16x16x32_bf16(Af[kt], Bf[n][kt], acc[n], 0, 0, 0);

        /* epilogue: p_r = csum_n - 2*INV_NORM * sum_n ctx_n/(1+e^{2(acc+bias)}) */
        float pr[4];
#pragma unroll
        for (int r = 0; r < 4; r++) {
            float psum = 0.f;
#pragma unroll
            for (int n = 0; n < 8; n++) {
                float t = fmaf(acc[n][r], 2.f, bias2[n]);
                float rc = __builtin_amdgcn_rcpf(1.f + __expf(t));
                psum = fmaf(ctx_r[n], rc, psum);
            }
            float p = fmaf(-2.f * INV_NORM, psum, csum_n);
#pragma unroll
            for (int o = 1; o < 16; o <<= 1) p += __shfl_xor(p, o);
            pr[r] = p;
        }
        if (col == 0) {
            int4 mv = ((const int4*)(mask + tbase))[q];
            float4 s;
            s.x = mv.x ? pr[0] : -1e9f;
            s.y = mv.y ? pr[1] : -1e9f;
            s.z = mv.z ? pr[2] : -1e9f;
            s.w = mv.w ? pr[3] : -1e9f;
            ((float4*)(scores + tbase))[q] = s;

            /* fused histogram (all tokens, mask-independent) */
            int4 iv = ((const int4*)(index + tbase))[q];
            int* cb = counts + (int)(tbase / N_) * IDX_;
            atomicAdd(&cb[iv.x], 1);
            atomicAdd(&cb[iv.y], 1);
            atomicAdd(&cb[iv.z], 1);
            atomicAdd(&cb[iv.w], 1);
        }
    }
}

/* ---------------- Kernel C: exclusive scan over 8192 counters --------------- */
__global__ __launch_bounds__(1024) void scan_kernel(
    const int* __restrict__ counts, int* __restrict__ offsets, int* __restrict__ cursor)
{
    __shared__ int sums[1024];
    int tid = threadIdx.x;
    int c[8], loc[8], s = 0;
#pragma unroll
    for (int j = 0; j < 8; j++) { c[j] = counts[tid * 8 + j]; loc[j] = s; s += c[j]; }
    sums[tid] = s;
    __syncthreads();
    for (int off = 1; off < 1024; off <<= 1) {
        int v = (tid >= off) ? sums[tid - off] : 0;
        __syncthreads();
        if (tid >= off) sums[tid] += v;
        __syncthreads();
    }
    int base = (tid > 0) ? sums[tid - 1] : 0;
#pragma unroll
    for (int j = 0; j < 8; j++) {
        int o = base + loc[j];
        offsets[tid * 8 + j] = o;
        cursor[tid * 8 + j]  = o;
    }
}

/* -------- Kernel D: scatter (token, score) pairs into segment lists --------
 * Reads index & scores COALESCED (linear token walk); the scattered part is
 * one int2 write per token. Emits ALL tokens (masked included) so attend has
 * the complete list for the all-masked-segment fallback. */
__global__ __launch_bounds__(256) void scatter_kernel(
    const int* __restrict__ index, const float* __restrict__ scores,
    int* __restrict__ cursor, int2* __restrict__ tokenlist)
{
    for (int tok = blockIdx.x * blockDim.x + threadIdx.x; tok < TT;
         tok += gridDim.x * blockDim.x) {
        int seg = index[tok];
        float s = scores[tok];
        int b   = tok / N_;
        int pos = atomicAdd(&cursor[b * IDX_ + seg], 1);
        tokenlist[pos] = make_int2(tok, __float_as_int(s));
    }
}

/* -------- Kernel E: wave-per-segment softmax + weighted sum ----------------
 * 4 waves/block, one (b,seg) each; shuffle-only reductions, zero syncthreads.
 * KEY CHANGE (R2): masked tokens (score = -1e9) have softmax weight exactly
 * 0.0 in fp32, so their x rows are never read. Unmasked tokens (~50%) are
 * wave-compacted (ballot/popc rank, order-preserving -> bit-identical sums)
 * into the LDS pair buffer; the x gather runs over the compacted list only.
 * This halves attend's x traffic: ~819 MB -> ~410 MB. */
__global__ __launch_bounds__(256) void attend_kernel(
    const float* __restrict__ x, const int* __restrict__ counts,
    const int* __restrict__ offsets, const int2* __restrict__ tokenlist,
    float* __restrict__ attn /* out: weights */, float* __restrict__ out)
{
    const int wave = threadIdx.x >> 6;
    const int lane = threadIdx.x & 63;
    const int key  = blockIdx.x * 4 + wave;   /* b*IDX + seg */
    const int cnt  = counts[key];
    const int off  = offsets[key];
    const float2* __restrict__ x2 = (const float2*)x;
    float2* out2 = (float2*)(out + (size_t)key * E_);

    __shared__ int2 pair[4][CAP];   /* 16 KiB, one slice per wave */

    if (cnt == 0) { out2[lane] = make_float2(0.f, 0.f); return; }

    if (cnt <= CAP) {
        /* ---- fast path: (t,s) in registers ---- */
        int   tk[RCAP];
        float sc[RCAP], ev[RCAP];
        bool  um[RCAP];                       /* unmasked? */
        float m = -INFINITY;
#pragma unroll
        for (int u = 0; u < RCAP; u++) {
            int j = lane + u * 64;
            um[u] = false;
            if (j < cnt) {
                int2 p = tokenlist[off + j];
                tk[u] = p.x;
                sc[u] = __int_as_float(p.y);
                if (sc[u] > -1e8f) { um[u] = true; m = fmaxf(m, sc[u]); }
            }
        }
#pragma unroll
        for (int o = 32; o; o >>= 1) m = fmaxf(m, __shfl_xor(m, o));

        int cnt2 = 0;   /* compacted (unmasked) count, wave-uniform */
        if (m > -INFINITY) {
            float sum = 0.f;
#pragma unroll
            for (int u = 0; u < RCAP; u++)
                if (um[u]) { ev[u] = __expf(sc[u] - m); sum += ev[u]; }
#pragma unroll
            for (int o = 32; o; o >>= 1) sum += __shfl_xor(sum, o);
            const float inv = 1.f / sum;

#pragma unroll
            for (int u = 0; u < RCAP; u++) {
                int j = lane + u * 64;
                unsigned long long bal = __ballot(um[u]);   /* wave-uniform exec */
                if (j < cnt) {
                    if (um[u]) {
                        float w = ev[u] * inv;
                        attn[tk[u]] = w;
                        int rank = (int)__popcll(bal & ((1ull << lane) - 1ull));
                        pair[wave][cnt2 + rank] = make_int2(tk[u], __float_as_int(w));
                    } else {
                        attn[tk[u]] = 0.f;    /* exp(-1e9 - m) underflows to +0 */
                    }
                }
                cnt2 += (int)__popcll(bal);
            }
        } else {
            /* all tokens masked: reference gives uniform weights 1/cnt */
            const float w = 1.f / (float)cnt;
#pragma unroll
            for (int u = 0; u < RCAP; u++) {
                int j = lane + u * 64;
                if (j < cnt) {
                    attn[tk[u]] = w;
                    pair[wave][j] = make_int2(tk[u], __float_as_int(w));
                }
            }
            cnt2 = cnt;
        }
        /* wave-synchronous: compiler inserts lgkmcnt before the reads below */

        float2 acc = make_float2(0.f, 0.f);
        int j = 0;
        for (; j + 3 < cnt2; j += 4) {
            int2 p0 = pair[wave][j];
            int2 p1 = pair[wave][j + 1];
            int2 p2 = pair[wave][j + 2];
            int2 p3 = pair[wave][j + 3];
            float2 a0 = x2[(size_t)p0.x * 64 + lane];
            float2 a1 = x2[(size_t)p1.x * 64 + lane];
            float2 a2 = x2[(size_t)p2.x * 64 + lane];
            float2 a3 = x2[(size_t)p3.x * 64 + lane];
            float w0 = __int_as_float(p0.y), w1 = __int_as_float(p1.y);
            float w2 = __int_as_float(p2.y), w3 = __int_as_float(p3.y);
            acc.x = fmaf(w0, a0.x, acc.x); acc.y = fmaf(w0, a0.y, acc.y);
            acc.x = fmaf(w1, a1.x, acc.x); acc.y = fmaf(w1, a1.y, acc.y);
            acc.x = fmaf(w2, a2.x, acc.x); acc.y = fmaf(w2, a2.y, acc.y);
            acc.x = fmaf(w3, a3.x, acc.x); acc.y = fmaf(w3, a3.y, acc.y);
        }
        for (; j < cnt2; j++) {
            int2  p = pair[wave][j];
            float2 a = x2[(size_t)p.x * 64 + lane];
            float w = __int_as_float(p.y);
            acc.x = fmaf(w, a.x, acc.x); acc.y = fmaf(w, a.y, acc.y);
        }
        out2[lane] = acc;
    } else {
        /* ---- slow path (cnt > CAP): never taken at these sizes ---- */
        float m = -INFINITY;
        for (int j = lane; j < cnt; j += 64)
            m = fmaxf(m, __int_as_float(tokenlist[off + j].y));
#pragma unroll
        for (int o = 32; o; o >>= 1) m = fmaxf(m, __shfl_xor(m, o));

        float sum = 0.f;
        for (int j = lane; j < cnt; j += 64)
            sum += __expf(__int_as_float(tokenlist[off + j].y) - m);
#pragma unroll
        for (int o = 32; o; o >>= 1) sum += __shfl_xor(sum, o);
        const float inv = 1.f / sum;

        float2 acc = make_float2(0.f, 0.f);
        for (int j0 = 0; j0 < cnt; j0 += 64) {
            int t = 0; float w = 0.f;
            if (j0 + lane < cnt) {
                int2 p = tokenlist[off + j0 + lane];
                t = p.x;
                w = __expf(__int_as_float(p.y) - m) * inv;
                attn[t] = w;
            }
            int lim = min(64, cnt - j0);
            for (int jj = 0; jj < lim; jj++) {
                int   tb = __shfl(t, jj);
                float wb = __shfl(w, jj);
                if (wb != 0.f) {
                    float2 a = x2[(size_t)tb * 64 + lane];
                    acc.x = fmaf(wb, a.x, acc.x);
                    acc.y = fmaf(wb, a.y, acc.y);
                }
            }
        }
        out2[lane] = acc;
    }
}

extern "C" void kernel_launch(void* const* d_in, const int* in_sizes, int n_in,
                              void* d_out, int out_size, void* d_ws, size_t ws_size,
                              hipStream_t stream)
{
    const float* x    = (const float*)d_in[0];
    const float* W    = (const float*)d_in[1];
    const float* bias = (const float*)d_in[2];
    const float* ctx  = (const float*)d_in[3];
    const int*   mask = (const int*)d_in[4];
    const int*   index= (const int*)d_in[5];

    float* out  = (float*)d_out;                         /* B*IDX*E */
    float* attn = out + (size_t)B_ * IDX_ * E_;          /* B*N: scores then weights */

    int* counts    = (int*)d_ws;
    int* offsets   = counts  + B_ * IDX_;
    int* cursor    = offsets + B_ * IDX_;
    int2* tokenlist = (int2*)(cursor + B_ * IDX_);       /* TT * 8 B */

    hipMemsetAsync(counts, 0, B_ * IDX_ * sizeof(int), stream);
    score_kernel  <<<2048, 256, 0, stream>>>(x, W, bias, ctx, mask, index, attn, counts);
    scan_kernel   <<<1, 1024, 0, stream>>>(counts, offsets, cursor);
    scatter_kernel<<<1024, 256, 0, stream>>>(index, attn, cursor, tokenlist);
    attend_kernel <<<B_ * IDX_ / 4, 256, 0, stream>>>(x, counts, offsets, tokenlist, attn, out);
}

// Round 3
// 659.505 us; speedup vs baseline: 1.1165x; 1.0593x over previous
//
#include <hip/hip_runtime.h>
#include <hip/hip_bf16.h>
#include <math.h>

#define B_    4
#define N_    200000
#define E_    128
#define IDX_  2048
#define TT    (B_*N_)
#define INV_NORM 0.08838834764831845f   /* 1/sqrt(128) */
#define CAP   512
#define RCAP  8                         /* 8*64 = 512 tokens in-register */
#define WPAD  136                       /* bf16 elems per W row in LDS */

typedef __attribute__((ext_vector_type(8))) short bf16x8;
typedef __attribute__((ext_vector_type(4))) float f32x4;

__device__ __forceinline__ unsigned short f2bf(float f) {
    unsigned int u = __float_as_uint(f);
    unsigned int r = (u + 0x7fffu + ((u >> 16) & 1u)) >> 16;
    return (unsigned short)r;
}

/* ---- Kernel A: scores via bf16 MFMA + fused histogram ----
 * s = mask ? ctx.tanh(x@W^T+b)/sqrt(E) : -1e9 ;  counts[b,idx]++
 * epilogue identity: ctx.tanh(v) = sum(ctx) - 2*sum(ctx/(1+e^{2v}))
 * R3: masked tokens' scores are discarded (-> -1e9), and the 16x16x32 C
 * layout maps each C row to exactly one token, so we SKIP the x-row loads
 * for masked lanes (A-row := 0). Unmasked scores stay bit-identical; x
 * fetch drops 409.6 -> ~205 MB. */
__global__ __launch_bounds__(256) void score_kernel(
    const float* __restrict__ x, const float* __restrict__ W,
    const float* __restrict__ bias, const float* __restrict__ ctx,
    const int* __restrict__ mask, const int* __restrict__ index,
    float* __restrict__ scores, int* __restrict__ counts)
{
    __shared__ unsigned short Wb[E_ * WPAD];   /* 34816 B */

    const int tid = threadIdx.x;

    /* stage W: fp32 global -> bf16 LDS (once per block) */
    for (int i = tid; i < E_ * E_ / 4; i += 256) {
        int f = i >> 5, kb = (i & 31) * 4;
        float4 v = ((const float4*)W)[i];
        ushort4 o;
        o.x = f2bf(v.x); o.y = f2bf(v.y); o.z = f2bf(v.z); o.w = f2bf(v.w);
        *(ushort4*)&Wb[f * WPAD + kb] = o;
    }
    __syncthreads();

    const int lane = tid & 63;
    const int col  = lane & 15;      /* feature-within-ntile / token-within-mtile */
    const int q    = lane >> 4;      /* quad: k-subrange for A/B, row-group for C */
    const int wave = tid >> 6;

    /* per-lane ctx / 2*bias for features n*16+col; csum = sum of this lane's ctx */
    float ctx_r[8], bias2[8], csum = 0.f;
#pragma unroll
    for (int n = 0; n < 8; n++) {
        ctx_r[n] = ctx[n * 16 + col];
        bias2[n] = 2.f * bias[n * 16 + col];
        csum += ctx_r[n];
    }
    const float csum_n = csum * INV_NORM;

    /* persistent B fragments: Bf[n][kt] = W[n*16+col][kt*32+q*8 .. +7] */
    bf16x8 Bf[8][4];
#pragma unroll
    for (int n = 0; n < 8; n++)
#pragma unroll
        for (int kt = 0; kt < 4; kt++)
            Bf[n][kt] = *(const bf16x8*)&Wb[(n * 16 + col) * WPAD + kt * 32 + q * 8];

    for (long base0 = (long)blockIdx.x * 64; base0 < TT; base0 += (long)gridDim.x * 64) {
        const long tbase = base0 + wave * 16;
        const float* xrow = x + (tbase + col) * (long)E_;

        /* per-lane row predicate: all 4 quads of a masked col skip the row */
        const int mrow = mask[tbase + col];

        /* A fragments: Af[kt] = x[tbase+col][kt*32+q*8 .. +7], fp32->bf16 packed */
        bf16x8 Af[4];
#pragma unroll
        for (int kt = 0; kt < 4; kt++)
            Af[kt] = (bf16x8){0, 0, 0, 0, 0, 0, 0, 0};
        if (mrow) {
#pragma unroll
            for (int kt = 0; kt < 4; kt++) {
                float4 u = ((const float4*)xrow)[kt * 8 + q * 2];
                float4 v = ((const float4*)xrow)[kt * 8 + q * 2 + 1];
                union { bf16x8 vec; __hip_bfloat162 h[4]; } a;
                a.h[0] = __float22bfloat162_rn(make_float2(u.x, u.y));
                a.h[1] = __float22bfloat162_rn(make_float2(u.z, u.w));
                a.h[2] = __float22bfloat162_rn(make_float2(v.x, v.y));
                a.h[3] = __float22bfloat162_rn(make_float2(v.z, v.w));
                Af[kt] = a.vec;
            }
        }

        f32x4 acc[8];
#pragma unroll
        for (int n = 0; n < 8; n++) acc[n] = (f32x4){0.f, 0.f, 0.f, 0.f};

#pragma unroll
        for (int kt = 0; kt < 4; kt++)
#pragma unroll
            for (int n = 0; n < 8; n++)
                acc[n] = __builtin_amdgcn_mfma_f32_16x16x32_bf16(Af[kt], Bf[n][kt], acc[n], 0, 0, 0);

        /* epilogue: p_r = csum_n - 2*INV_NORM * sum_n ctx_n/(1+e^{2(acc+bias)}) */
        float pr[4];
#pragma unroll
        for (int r = 0; r < 4; r++) {
            float psum = 0.f;
#pragma unroll
            for (int n = 0; n < 8; n++) {
                float t = fmaf(acc[n][r], 2.f, bias2[n]);
                float rc = __builtin_amdgcn_rcpf(1.f + __expf(t));
                psum = fmaf(ctx_r[n], rc, psum);
            }
            float p = fmaf(-2.f * INV_NORM, psum, csum_n);
#pragma unroll
            for (int o = 1; o < 16; o <<= 1) p += __shfl_xor(p, o);
            pr[r] = p;
        }
        if (col == 0) {
            int4 mv = ((const int4*)(mask + tbase))[q];
            float4 s;
            s.x = mv.x ? pr[0] : -1e9f;
            s.y = mv.y ? pr[1] : -1e9f;
            s.z = mv.z ? pr[2] : -1e9f;
            s.w = mv.w ? pr[3] : -1e9f;
            ((float4*)(scores + tbase))[q] = s;

            /* fused histogram (all tokens, mask-independent) */
            int4 iv = ((const int4*)(index + tbase))[q];
            int* cb = counts + (int)(tbase / N_) * IDX_;
            atomicAdd(&cb[iv.x], 1);
            atomicAdd(&cb[iv.y], 1);
            atomicAdd(&cb[iv.z], 1);
            atomicAdd(&cb[iv.w], 1);
        }
    }
}

/* ---------------- Kernel C: exclusive scan over 8192 counters --------------- */
__global__ __launch_bounds__(1024) void scan_kernel(
    const int* __restrict__ counts, int* __restrict__ offsets, int* __restrict__ cursor)
{
    __shared__ int sums[1024];
    int tid = threadIdx.x;
    int c[8], loc[8], s = 0;
#pragma unroll
    for (int j = 0; j < 8; j++) { c[j] = counts[tid * 8 + j]; loc[j] = s; s += c[j]; }
    sums[tid] = s;
    __syncthreads();
    for (int off = 1; off < 1024; off <<= 1) {
        int v = (tid >= off) ? sums[tid - off] : 0;
        __syncthreads();
        if (tid >= off) sums[tid] += v;
        __syncthreads();
    }
    int base = (tid > 0) ? sums[tid - 1] : 0;
#pragma unroll
    for (int j = 0; j < 8; j++) {
        int o = base + loc[j];
        offsets[tid * 8 + j] = o;
        cursor[tid * 8 + j]  = o;
    }
}

/* -------- Kernel D: scatter (token, score) pairs into segment lists --------
 * Reads index & scores COALESCED (linear token walk); the scattered part is
 * one int2 write per token. Emits ALL tokens (masked included) so attend has
 * the complete list for the all-masked-segment fallback. */
__global__ __launch_bounds__(256) void scatter_kernel(
    const int* __restrict__ index, const float* __restrict__ scores,
    int* __restrict__ cursor, int2* __restrict__ tokenlist)
{
    for (int tok = blockIdx.x * blockDim.x + threadIdx.x; tok < TT;
         tok += gridDim.x * blockDim.x) {
        int seg = index[tok];
        float s = scores[tok];
        int b   = tok / N_;
        int pos = atomicAdd(&cursor[b * IDX_ + seg], 1);
        tokenlist[pos] = make_int2(tok, __float_as_int(s));
    }
}

/* -------- Kernel E: wave-per-segment softmax + weighted sum ----------------
 * 4 waves/block, one (b,seg) each; shuffle-only reductions, zero syncthreads.
 * Masked tokens (score = -1e9) have softmax weight exactly 0.0 in fp32, so
 * their x rows are never read: unmasked tokens (~50%) are wave-compacted
 * (ballot/popc rank, order-preserving -> bit-identical sums) into the LDS
 * pair buffer; the x gather runs over the compacted list only. */
__global__ __launch_bounds__(256) void attend_kernel(
    const float* __restrict__ x, const int* __restrict__ counts,
    const int* __restrict__ offsets, const int2* __restrict__ tokenlist,
    float* __restrict__ attn /* out: weights */, float* __restrict__ out)
{
    const int wave = threadIdx.x >> 6;
    const int lane = threadIdx.x & 63;
    const int key  = blockIdx.x * 4 + wave;   /* b*IDX + seg */
    const int cnt  = counts[key];
    const int off  = offsets[key];
    const float2* __restrict__ x2 = (const float2*)x;
    float2* out2 = (float2*)(out + (size_t)key * E_);

    __shared__ int2 pair[4][CAP];   /* 16 KiB, one slice per wave */

    if (cnt == 0) { out2[lane] = make_float2(0.f, 0.f); return; }

    if (cnt <= CAP) {
        /* ---- fast path: (t,s) in registers ---- */
        int   tk[RCAP];
        float sc[RCAP], ev[RCAP];
        bool  um[RCAP];                       /* unmasked? */
        float m = -INFINITY;
#pragma unroll
        for (int u = 0; u < RCAP; u++) {
            int j = lane + u * 64;
            um[u] = false;
            if (j < cnt) {
                int2 p = tokenlist[off + j];
                tk[u] = p.x;
                sc[u] = __int_as_float(p.y);
                if (sc[u] > -1e8f) { um[u] = true; m = fmaxf(m, sc[u]); }
            }
        }
#pragma unroll
        for (int o = 32; o; o >>= 1) m = fmaxf(m, __shfl_xor(m, o));

        int cnt2 = 0;   /* compacted (unmasked) count, wave-uniform */
        if (m > -INFINITY) {
            float sum = 0.f;
#pragma unroll
            for (int u = 0; u < RCAP; u++)
                if (um[u]) { ev[u] = __expf(sc[u] - m); sum += ev[u]; }
#pragma unroll
            for (int o = 32; o; o >>= 1) sum += __shfl_xor(sum, o);
            const float inv = 1.f / sum;

#pragma unroll
            for (int u = 0; u < RCAP; u++) {
                int j = lane + u * 64;
                unsigned long long bal = __ballot(um[u]);   /* wave-uniform exec */
                if (j < cnt) {
                    if (um[u]) {
                        float w = ev[u] * inv;
                        attn[tk[u]] = w;
                        int rank = (int)__popcll(bal & ((1ull << lane) - 1ull));
                        pair[wave][cnt2 + rank] = make_int2(tk[u], __float_as_int(w));
                    } else {
                        attn[tk[u]] = 0.f;    /* exp(-1e9 - m) underflows to +0 */
                    }
                }
                cnt2 += (int)__popcll(bal);
            }
        } else {
            /* all tokens masked: reference gives uniform weights 1/cnt */
            const float w = 1.f / (float)cnt;
#pragma unroll
            for (int u = 0; u < RCAP; u++) {
                int j = lane + u * 64;
                if (j < cnt) {
                    attn[tk[u]] = w;
                    pair[wave][j] = make_int2(tk[u], __float_as_int(w));
                }
            }
            cnt2 = cnt;
        }
        /* wave-synchronous: compiler inserts lgkmcnt before the reads below */

        float2 acc = make_float2(0.f, 0.f);
        int j = 0;
        for (; j + 3 < cnt2; j += 4) {
            int2 p0 = pair[wave][j];
            int2 p1 = pair[wave][j + 1];
            int2 p2 = pair[wave][j + 2];
            int2 p3 = pair[wave][j + 3];
            float2 a0 = x2[(size_t)p0.x * 64 + lane];
            float2 a1 = x2[(size_t)p1.x * 64 + lane];
            float2 a2 = x2[(size_t)p2.x * 64 + lane];
            float2 a3 = x2[(size_t)p3.x * 64 + lane];
            float w0 = __int_as_float(p0.y), w1 = __int_as_float(p1.y);
            float w2 = __int_as_float(p2.y), w3 = __int_as_float(p3.y);
            acc.x = fmaf(w0, a0.x, acc.x); acc.y = fmaf(w0, a0.y, acc.y);
            acc.x = fmaf(w1, a1.x, acc.x); acc.y = fmaf(w1, a1.y, acc.y);
            acc.x = fmaf(w2, a2.x, acc.x); acc.y = fmaf(w2, a2.y, acc.y);
            acc.x = fmaf(w3, a3.x, acc.x); acc.y = fmaf(w3, a3.y, acc.y);
        }
        for (; j < cnt2; j++) {
            int2  p = pair[wave][j];
            float2 a = x2[(size_t)p.x * 64 + lane];
            float w = __int_as_float(p.y);
            acc.x = fmaf(w, a.x, acc.x); acc.y = fmaf(w, a.y, acc.y);
        }
        out2[lane] = acc;
    } else {
        /* ---- slow path (cnt > CAP): never taken at these sizes ---- */
        float m = -INFINITY;
        for (int j = lane; j < cnt; j += 64)
            m = fmaxf(m, __int_as_float(tokenlist[off + j].y));
#pragma unroll
        for (int o = 32; o; o >>= 1) m = fmaxf(m, __shfl_xor(m, o));

        float sum = 0.f;
        for (int j = lane; j < cnt; j += 64)
            sum += __expf(__int_as_float(tokenlist[off + j].y) - m);
#pragma unroll
        for (int o = 32; o; o >>= 1) sum += __shfl_xor(sum, o);
        const float inv = 1.f / sum;

        float2 acc = make_float2(0.f, 0.f);
        for (int j0 = 0; j0 < cnt; j0 += 64) {
            int t = 0; float w = 0.f;
            if (j0 + lane < cnt) {
                int2 p = tokenlist[off + j0 + lane];
                t = p.x;
                w = __expf(__int_as_float(p.y) - m) * inv;
                attn[t] = w;
            }
            int lim = min(64, cnt - j0);
            for (int jj = 0; jj < lim; jj++) {
                int   tb = __shfl(t, jj);
                float wb = __shfl(w, jj);
                if (wb != 0.f) {
                    float2 a = x2[(size_t)tb * 64 + lane];
                    acc.x = fmaf(wb, a.x, acc.x);
                    acc.y = fmaf(wb, a.y, acc.y);
                }
            }
        }
        out2[lane] = acc;
    }
}

extern "C" void kernel_launch(void* const* d_in, const int* in_sizes, int n_in,
                              void* d_out, int out_size, void* d_ws, size_t ws_size,
                              hipStream_t stream)
{
    const float* x    = (const float*)d_in[0];
    const float* W    = (const float*)d_in[1];
    const float* bias = (const float*)d_in[2];
    const float* ctx  = (const float*)d_in[3];
    const int*   mask = (const int*)d_in[4];
    const int*   index= (const int*)d_in[5];

    float* out  = (float*)d_out;                         /* B*IDX*E */
    float* attn = out + (size_t)B_ * IDX_ * E_;          /* B*N: scores then weights */

    int* counts    = (int*)d_ws;
    int* offsets   = counts  + B_ * IDX_;
    int* cursor    = offsets + B_ * IDX_;
    int2* tokenlist = (int2*)(cursor + B_ * IDX_);       /* TT * 8 B */

    hipMemsetAsync(counts, 0, B_ * IDX_ * sizeof(int), stream);
    score_kernel  <<<2048, 256, 0, stream>>>(x, W, bias, ctx, mask, index, attn, counts);
    scan_kernel   <<<1, 1024, 0, stream>>>(counts, offsets, cursor);
    scatter_kernel<<<1024, 256, 0, stream>>>(index, attn, cursor, tokenlist);
    attend_kernel <<<B_ * IDX_ / 4, 256, 0, stream>>>(x, counts, offsets, tokenlist, attn, out);
}